// Round 4
// baseline (100.470 us; speedup 1.0000x reference)
//
#include <hip/hip_runtime.h>
#include <stdint.h>

// 24x24-bit binary multiplier on float bit-vectors.
// A,B: [131072,24] LSB-first {0.0,1.0}; out: [131072,48] LSB-first bits of a*b.
// Reference's partial-product + ripple-carry tree == integer multiply (no
// overflow at 24x24 -> 48 bits): pack bits -> u64 imul -> unpack bits.
//
// R4 = DECOMPOSITION PROBE. Identical kernel to R3 (wave-autonomous, shfl
// redistribution, all global accesses lane-contiguous), but launched 4x
// back-to-back (idempotent rewrites). Purpose: measure the kernel's true
// per-launch time as (dur_us - 75.6)/3, since the harness's re-poison fill
// train (~256MB ws fill @ 43us + out fill + input restores) hides the kernel
// below the rocprof top-5 cutoff. If the increment is ~6-9us/launch, the
// kernel is at the memory roofline and dur_us is harness-floor-dominated.

#define NBATCH 131072
#define ROWS_PER_WAVE 32
#define N_WAVES (NBATCH / ROWS_PER_WAVE)     // 4096
#define WAVES_PER_BLOCK 4
#define N_BLOCKS (N_WAVES / WAVES_PER_BLOCK) // 1024

__global__ __launch_bounds__(256) void ArrayMultiplier24x24_kernel(
    const uint4* __restrict__ A4,   // bit-pattern view of floats, 6 f4/row
    const uint4* __restrict__ B4,
    float4* __restrict__ O4)        // 12 f4/row
{
    const int l = threadIdx.x & 63;
    const int w = blockIdx.x * WAVES_PER_BLOCK + (threadIdx.x >> 6);
    const size_t inBase  = (size_t)w * (ROWS_PER_WAVE * 6);   // 192 f4
    const size_t outBase = (size_t)w * (ROWS_PER_WAVE * 12);  // 384 f4

    // Phase 1: lane-contiguous loads; pack each f4 (4 floats in {0,1}) to a
    // nibble. 1.0f = 0x3F800000 -> bit = (u >> 29) & 1.
    uint32_t nA[3], nB[3];
#pragma unroll
    for (int k = 0; k < 3; ++k) {
        uint4 va = A4[inBase + k * 64 + l];
        uint4 vb = B4[inBase + k * 64 + l];
        nA[k] = ((va.x >> 29) & 1u) | ((va.y >> 28) & 2u) |
                ((va.z >> 27) & 4u) | ((va.w >> 26) & 8u);
        nB[k] = ((vb.x >> 29) & 1u) | ((vb.y >> 28) & 2u) |
                ((vb.z >> 27) & 4u) | ((vb.w >> 26) & 8u);
    }

    // Phase 2: gather row r's 6 nibbles via shuffles. Row r's s-th nibble
    // lives at flat f4 index r*6+s = reg (idx>>6), lane (idx&63).
    const int r = l & 31;
    uint32_t a = 0u, b = 0u;
#pragma unroll
    for (int s = 0; s < 6; ++s) {
        int idx = r * 6 + s;
        int src = idx & 63;
        int k   = idx >> 6;            // 0..2
        uint32_t a0 = __shfl(nA[0], src, 64);
        uint32_t a1 = __shfl(nA[1], src, 64);
        uint32_t a2 = __shfl(nA[2], src, 64);
        uint32_t b0 = __shfl(nB[0], src, 64);
        uint32_t b1 = __shfl(nB[1], src, 64);
        uint32_t b2 = __shfl(nB[2], src, 64);
        uint32_t av = (k == 0) ? a0 : ((k == 1) ? a1 : a2);
        uint32_t bv = (k == 0) ? b0 : ((k == 1) ? b1 : b2);
        a |= av << (4 * s);
        b |= bv << (4 * s);
    }

    // The multiply (lane r holds row r's product).
    uint64_t p = (uint64_t)a * (uint64_t)b;
    uint32_t plo = (uint32_t)p, phi = (uint32_t)(p >> 32);

    // Phase 3: lane-contiguous stores. Output f4 g (0..383) = row g/12,
    // bits (g%12)*4 .. +3 of that row's product (fetched from lane g/12).
#pragma unroll
    for (int k = 0; k < 6; ++k) {
        int g = k * 64 + l;
        int row = g / 12;                  // 0..31 (magic-mul)
        int c0 = (g - row * 12) * 4;       // 0..44
        uint32_t lo = __shfl(plo, row, 64);
        uint32_t hi = __shfl(phi, row, 64);
        uint64_t pp = ((uint64_t)hi << 32) | lo;
        uint32_t bits = (uint32_t)(pp >> c0);
        float4 v;
        v.x = (float)(bits & 1u);
        v.y = (float)((bits >> 1) & 1u);
        v.z = (float)((bits >> 2) & 1u);
        v.w = (float)((bits >> 3) & 1u);
        O4[outBase + g] = v;
    }
}

extern "C" void kernel_launch(void* const* d_in, const int* in_sizes, int n_in,
                              void* d_out, int out_size, void* d_ws, size_t ws_size,
                              hipStream_t stream)
{
    const uint4* A4 = (const uint4*)d_in[0];
    const uint4* B4 = (const uint4*)d_in[1];
    float4* O4 = (float4*)d_out;

    // 4x identical idempotent launches: probe to measure per-launch kernel
    // time as the dur_us increment over the single-launch R3 baseline.
    ArrayMultiplier24x24_kernel<<<N_BLOCKS, 256, 0, stream>>>(A4, B4, O4);
    ArrayMultiplier24x24_kernel<<<N_BLOCKS, 256, 0, stream>>>(A4, B4, O4);
    ArrayMultiplier24x24_kernel<<<N_BLOCKS, 256, 0, stream>>>(A4, B4, O4);
    ArrayMultiplier24x24_kernel<<<N_BLOCKS, 256, 0, stream>>>(A4, B4, O4);
}

// Round 5
// 76.806 us; speedup vs baseline: 1.3081x; 1.3081x over previous
//
#include <hip/hip_runtime.h>
#include <stdint.h>

// 24x24-bit binary multiplier on float bit-vectors.
// A,B: [131072,24] LSB-first {0.0,1.0}; out: [131072,48] LSB-first bits of a*b.
// Reference's partial-product + ripple-carry tree == integer multiply (no
// overflow at 24x24 -> 48 bits): pack bits -> u64 imul -> unpack bits.
//
// FINAL (= R3, probe reverted). Wave-autonomous: each wave owns 32 rows;
// all global accesses are lane-contiguous (3 uint4 loads/operand, 6 float4
// stores per wave); cross-lane bit redistribution via __shfl. No LDS, no
// barriers. 1024 blocks x 256.
//
// Measured decomposition (R4 4x-launch probe): kernel ~8.3us/launch warm =
// 50.3 MB @ ~6.1 TB/s = 96% of achievable HBM BW (6.3 TB/s). The remaining
// ~67us of dur_us is the harness's per-iteration re-poison train (256 MB ws
// fill @ 43us + out fill + input restores) — not addressable from the kernel.

#define NBATCH 131072
#define ROWS_PER_WAVE 32
#define N_WAVES (NBATCH / ROWS_PER_WAVE)     // 4096
#define WAVES_PER_BLOCK 4
#define N_BLOCKS (N_WAVES / WAVES_PER_BLOCK) // 1024

__global__ __launch_bounds__(256) void ArrayMultiplier24x24_kernel(
    const uint4* __restrict__ A4,   // bit-pattern view of floats, 6 f4/row
    const uint4* __restrict__ B4,
    float4* __restrict__ O4)        // 12 f4/row
{
    const int l = threadIdx.x & 63;
    const int w = blockIdx.x * WAVES_PER_BLOCK + (threadIdx.x >> 6);
    const size_t inBase  = (size_t)w * (ROWS_PER_WAVE * 6);   // 192 f4
    const size_t outBase = (size_t)w * (ROWS_PER_WAVE * 12);  // 384 f4

    // Phase 1: lane-contiguous loads; pack each f4 (4 floats in {0,1}) to a
    // nibble. 1.0f = 0x3F800000 -> bit = (u >> 29) & 1.
    uint32_t nA[3], nB[3];
#pragma unroll
    for (int k = 0; k < 3; ++k) {
        uint4 va = A4[inBase + k * 64 + l];
        uint4 vb = B4[inBase + k * 64 + l];
        nA[k] = ((va.x >> 29) & 1u) | ((va.y >> 28) & 2u) |
                ((va.z >> 27) & 4u) | ((va.w >> 26) & 8u);
        nB[k] = ((vb.x >> 29) & 1u) | ((vb.y >> 28) & 2u) |
                ((vb.z >> 27) & 4u) | ((vb.w >> 26) & 8u);
    }

    // Phase 2: gather row r's 6 nibbles via shuffles. Row r's s-th nibble
    // lives at flat f4 index r*6+s = reg (idx>>6), lane (idx&63).
    const int r = l & 31;
    uint32_t a = 0u, b = 0u;
#pragma unroll
    for (int s = 0; s < 6; ++s) {
        int idx = r * 6 + s;
        int src = idx & 63;
        int k   = idx >> 6;            // 0..2
        uint32_t a0 = __shfl(nA[0], src, 64);
        uint32_t a1 = __shfl(nA[1], src, 64);
        uint32_t a2 = __shfl(nA[2], src, 64);
        uint32_t b0 = __shfl(nB[0], src, 64);
        uint32_t b1 = __shfl(nB[1], src, 64);
        uint32_t b2 = __shfl(nB[2], src, 64);
        uint32_t av = (k == 0) ? a0 : ((k == 1) ? a1 : a2);
        uint32_t bv = (k == 0) ? b0 : ((k == 1) ? b1 : b2);
        a |= av << (4 * s);
        b |= bv << (4 * s);
    }

    // The multiply (lane r holds row r's product).
    uint64_t p = (uint64_t)a * (uint64_t)b;
    uint32_t plo = (uint32_t)p, phi = (uint32_t)(p >> 32);

    // Phase 3: lane-contiguous stores. Output f4 g (0..383) = row g/12,
    // bits (g%12)*4 .. +3 of that row's product (fetched from lane g/12).
#pragma unroll
    for (int k = 0; k < 6; ++k) {
        int g = k * 64 + l;
        int row = g / 12;                  // 0..31 (magic-mul)
        int c0 = (g - row * 12) * 4;       // 0..44
        uint32_t lo = __shfl(plo, row, 64);
        uint32_t hi = __shfl(phi, row, 64);
        uint64_t pp = ((uint64_t)hi << 32) | lo;
        uint32_t bits = (uint32_t)(pp >> c0);
        float4 v;
        v.x = (float)(bits & 1u);
        v.y = (float)((bits >> 1) & 1u);
        v.z = (float)((bits >> 2) & 1u);
        v.w = (float)((bits >> 3) & 1u);
        O4[outBase + g] = v;
    }
}

extern "C" void kernel_launch(void* const* d_in, const int* in_sizes, int n_in,
                              void* d_out, int out_size, void* d_ws, size_t ws_size,
                              hipStream_t stream)
{
    const uint4* A4 = (const uint4*)d_in[0];
    const uint4* B4 = (const uint4*)d_in[1];
    float4* O4 = (float4*)d_out;

    ArrayMultiplier24x24_kernel<<<N_BLOCKS, 256, 0, stream>>>(A4, B4, O4);
}